// Round 2
// baseline (501.380 us; speedup 1.0000x reference)
//
#include <hip/hip_runtime.h>
#include <hip/hip_bf16.h>

// Problem dims (hard-coded): B=4, C=256, F=16, H=32, W=32 (fp32 in/out)
#define CC 256
#define FF 16
#define PP 1024
#define BB 4
#define NN 64   // B*F

// ---------------------------------------------------------------------------
// Pass A: QKV projection. For each n in [0,64):  Y[d][p] = sum_c W[d][c]*X[c][p] + b[d]
// X = xr[n] (raw reinterpretation of x as [N][C][P]), fp32.
// Q,K -> ws (bf16, layout [n][d][p]); V -> d_out (fp32, layout [b][d][f][p]).
// Tile: 64 d x 64 p per block, K-chunk 16. 256 threads, 4x4 micro-tile x 3 projections.
// ---------------------------------------------------------------------------
__global__ __launch_bounds__(256) void qkv_kernel(
    const float* __restrict__ x,
    const float* __restrict__ wq, const float* __restrict__ bq,
    const float* __restrict__ wk, const float* __restrict__ bk,
    const float* __restrict__ wv, const float* __restrict__ bv,
    __hip_bfloat16* __restrict__ Qw, __hip_bfloat16* __restrict__ Kw,
    float* __restrict__ Vout)
{
    __shared__ float Xs[16][64];        // [c-chunk][p]
    __shared__ float Ws[3][16][64];     // [proj][c-chunk][d]  (transposed for inner reads)

    const int n  = blockIdx.z;
    const int d0 = blockIdx.y * 64;
    const int p0 = blockIdx.x * 64;
    const int t  = threadIdx.x;
    const int tx = t & 15;   // p direction
    const int ty = t >> 4;   // d direction

    float acc[3][4][4];
    #pragma unroll
    for (int pr = 0; pr < 3; ++pr)
        #pragma unroll
        for (int i = 0; i < 4; ++i)
            #pragma unroll
            for (int j = 0; j < 4; ++j) acc[pr][i][j] = 0.f;

    const float* xn = x + (size_t)n * CC * PP;

    for (int c0 = 0; c0 < CC; c0 += 16) {
        // stage X tile: 16 rows x 64 cols, coalesced across threads
        {
            const int col = t & 63;
            const int r0  = (t >> 6) * 4;
            #pragma unroll
            for (int rr = 0; rr < 4; ++rr) {
                Xs[r0 + rr][col] = xn[(size_t)(c0 + r0 + rr) * PP + p0 + col];
            }
        }
        // stage W tiles (transposed): Ws[pr][cc][dl] = w[(d0+dl)*C + c0+cc]
        {
            const int e0  = t * 4;
            const int dl  = e0 >> 4;
            const int cc0 = e0 & 15;
            const size_t rowbase = (size_t)(d0 + dl) * CC + c0 + cc0;
            #pragma unroll
            for (int j = 0; j < 4; ++j) Ws[0][cc0 + j][dl] = wq[rowbase + j];
            #pragma unroll
            for (int j = 0; j < 4; ++j) Ws[1][cc0 + j][dl] = wk[rowbase + j];
            #pragma unroll
            for (int j = 0; j < 4; ++j) Ws[2][cc0 + j][dl] = wv[rowbase + j];
        }
        __syncthreads();

        #pragma unroll
        for (int kk = 0; kk < 16; ++kk) {
            float xv[4];
            #pragma unroll
            for (int j = 0; j < 4; ++j) xv[j] = Xs[kk][tx * 4 + j];
            float wv3[3][4];
            #pragma unroll
            for (int pr = 0; pr < 3; ++pr)
                #pragma unroll
                for (int i = 0; i < 4; ++i) wv3[pr][i] = Ws[pr][kk][ty * 4 + i];
            #pragma unroll
            for (int pr = 0; pr < 3; ++pr)
                #pragma unroll
                for (int i = 0; i < 4; ++i)
                    #pragma unroll
                    for (int j = 0; j < 4; ++j)
                        acc[pr][i][j] += wv3[pr][i] * xv[j];
        }
        __syncthreads();
    }

    // epilogue: add bias, write Q,K (ws, bf16) and V (d_out, fp32, final layout)
    const int b = n >> 4, f = n & 15;
    #pragma unroll
    for (int i = 0; i < 4; ++i) {
        const int d = d0 + ty * 4 + i;
        const float bqv = bq[d];
        const float bkv = bk[d];
        const float bvv = bv[d];
        #pragma unroll
        for (int j = 0; j < 4; ++j) {
            const int p = p0 + tx * 4 + j;
            const size_t qk_idx = ((size_t)n * CC + d) * PP + p;
            Qw[qk_idx] = __float2bfloat16(acc[0][i][j] + bqv);
            Kw[qk_idx] = __float2bfloat16(acc[1][i][j] + bkv);
            const size_t v_idx = (((size_t)b * CC + d) * FF + f) * PP + p;
            Vout[v_idx] = acc[2][i][j] + bvv;
        }
    }
}

// ---------------------------------------------------------------------------
// Pass B: S[f1][f2] = (1/16) * sum_p Q[b*16+f1][d][p] * K[b*16+f2][d][p]; softmax over f2.
// One block per (b,d). 256 threads = 256 (f1,f2) pairs.
// ---------------------------------------------------------------------------
__global__ __launch_bounds__(256) void attn_kernel(
    const __hip_bfloat16* __restrict__ Qw, const __hip_bfloat16* __restrict__ Kw,
    float* __restrict__ attn)
{
    const int d = blockIdx.x;
    const int b = blockIdx.y;
    const int t = threadIdx.x;
    const int f1 = t >> 4, f2 = t & 15;

    __shared__ float Qs[16][65];
    __shared__ float Ks[16][65];

    float s = 0.f;
    for (int p0 = 0; p0 < PP; p0 += 64) {
        const int e  = t * 4;
        const int fr = e >> 6;       // frame row [0,16)
        const int pq = e & 63;       // p within chunk
        const size_t gbase = (((size_t)(b * 16 + fr)) * CC + d) * PP + p0 + pq;
        #pragma unroll
        for (int j = 0; j < 4; ++j) {
            Qs[fr][pq + j] = __bfloat162float(Qw[gbase + j]);
            Ks[fr][pq + j] = __bfloat162float(Kw[gbase + j]);
        }
        __syncthreads();
        #pragma unroll
        for (int pp2 = 0; pp2 < 64; ++pp2)
            s += Qs[f1][pp2] * Ks[f2][pp2];
        __syncthreads();
    }
    s *= 0.0625f;  // 1/sqrt(256)

    __shared__ float Sl[16][17];
    Sl[f1][f2] = s;
    __syncthreads();
    float m = -1e30f;
    #pragma unroll
    for (int j = 0; j < 16; ++j) m = fmaxf(m, Sl[f1][j]);
    float den = 0.f;
    #pragma unroll
    for (int j = 0; j < 16; ++j) den += __expf(Sl[f1][j] - m);
    const float a = __expf(s - m) / den;
    attn[(((size_t)b * CC + d) * 16 + f1) * 16 + f2] = a;
}

// ---------------------------------------------------------------------------
// Pass C: out[b][d][f1][p] = gamma * sum_f2 attn[b][d][f1][f2]*V[b][d][f2][p] + x[b][d][f1][p]
// V lives in d_out (written by pass A); update is in-place: each thread reads its 16 V
// values into registers before writing its 16 outputs (same addresses, same thread).
// One block per (b, d, p-tile of 256).
// ---------------------------------------------------------------------------
__global__ __launch_bounds__(256) void out_kernel(
    const float* __restrict__ attn,
    const float* __restrict__ x,
    const float* __restrict__ gamma,
    float* __restrict__ out)
{
    const int b = blockIdx.z;
    const int d = blockIdx.y;
    const int p = blockIdx.x * 256 + threadIdx.x;
    const int t = threadIdx.x;

    __shared__ float As[16][17];
    As[t >> 4][t & 15] = attn[(((size_t)b * CC + d) * 256) + t];

    const float g = gamma[0];
    const size_t base = (((size_t)b * CC + d) * FF) * PP + p;

    float vv[16];
    #pragma unroll
    for (int f2 = 0; f2 < 16; ++f2) vv[f2] = out[base + (size_t)f2 * PP];
    __syncthreads();

    #pragma unroll
    for (int f1 = 0; f1 < 16; ++f1) {
        float acc = 0.f;
        #pragma unroll
        for (int f2 = 0; f2 < 16; ++f2) acc += As[f1][f2] * vv[f2];
        const float res = g * acc + x[base + (size_t)f1 * PP];
        out[base + (size_t)f1 * PP] = res;
    }
}

extern "C" void kernel_launch(void* const* d_in, const int* in_sizes, int n_in,
                              void* d_out, int out_size, void* d_ws, size_t ws_size,
                              hipStream_t stream) {
    const float* x     = (const float*)d_in[0];
    const float* wq    = (const float*)d_in[1];
    const float* bq    = (const float*)d_in[2];
    const float* wk    = (const float*)d_in[3];
    const float* bk    = (const float*)d_in[4];
    const float* wv    = (const float*)d_in[5];
    const float* bv    = (const float*)d_in[6];
    const float* gamma = (const float*)d_in[7];
    float* out = (float*)d_out;

    __hip_bfloat16* Qw = (__hip_bfloat16*)d_ws;                  // 32 MiB
    __hip_bfloat16* Kw = Qw + (size_t)NN * CC * PP;              // 32 MiB
    float* attn = (float*)(Kw + (size_t)NN * CC * PP);           // 1 MiB

    // Pass A: QKV projections (V straight into d_out in final layout)
    qkv_kernel<<<dim3(PP / 64, CC / 64, NN), 256, 0, stream>>>(
        x, wq, bq, wk, bk, wv, bv, Qw, Kw, out);
    // Pass B: scores + softmax
    attn_kernel<<<dim3(CC, BB), 256, 0, stream>>>(Qw, Kw, attn);
    // Pass C: attn @ V + gamma*out + x (in-place on d_out)
    out_kernel<<<dim3(PP / 256, CC, BB), 256, 0, stream>>>(attn, x, gamma, out);
}

// Round 3
// 269.769 us; speedup vs baseline: 1.8586x; 1.8586x over previous
//
#include <hip/hip_runtime.h>
#include <hip/hip_bf16.h>

// Problem dims (hard-coded): B=4, C=256, F=16, H=32, W=32 (fp32 in/out)
#define CC 256
#define FF 16
#define PP 1024
#define BB 4
#define NN 64   // B*F

typedef __bf16 bf16x8 __attribute__((ext_vector_type(8)));
typedef float  f32x4  __attribute__((ext_vector_type(4)));

// ---------------------------------------------------------------------------
// xt_kernel: Xt[n][p][c] (bf16) = x[n][c][p] (fp32).  64x64 LDS tile transpose.
// ---------------------------------------------------------------------------
__global__ __launch_bounds__(256) void xt_kernel(
    const float* __restrict__ x, __hip_bfloat16* __restrict__ Xt)
{
    __shared__ float T[64][65];
    const int n = blockIdx.z, c0 = blockIdx.y * 64, p0 = blockIdx.x * 64;
    const int t = threadIdx.x;
    const int pl = t & 63, r0 = t >> 6;          // load: lane along p, 4 row groups
    const float* xp = x + ((size_t)n * CC + c0) * PP + p0;
    #pragma unroll
    for (int i = 0; i < 16; ++i) {
        const int cl = r0 + i * 4;
        T[cl][pl] = xp[(size_t)cl * PP + pl];
    }
    __syncthreads();
    __hip_bfloat16* op = Xt + ((size_t)n * PP + p0) * CC + c0;
    const int cl2 = t & 63, q0 = t >> 6;         // store: lane along c
    #pragma unroll
    for (int j = 0; j < 16; ++j) {
        const int pr = q0 + j * 4;
        op[(size_t)pr * CC + cl2] = __float2bfloat16(T[cl2][pr]);
    }
}

// ---------------------------------------------------------------------------
// wconv_kernel: Wb[proj][d][c] (bf16) from wq/wk/wv (fp32). 65536 elems/proj.
// ---------------------------------------------------------------------------
__global__ __launch_bounds__(256) void wconv_kernel(
    const float* __restrict__ wq, const float* __restrict__ wk,
    const float* __restrict__ wv, __hip_bfloat16* __restrict__ Wb)
{
    const int proj = blockIdx.y;
    const float* src = proj == 0 ? wq : (proj == 1 ? wk : wv);
    __hip_bfloat16* dst = Wb + (size_t)proj * CC * CC;
    const int idx = (blockIdx.x * 256 + threadIdx.x) * 4;
    const float4 v = *(const float4*)(src + idx);
    dst[idx + 0] = __float2bfloat16(v.x);
    dst[idx + 1] = __float2bfloat16(v.y);
    dst[idx + 2] = __float2bfloat16(v.z);
    dst[idx + 3] = __float2bfloat16(v.w);
}

// ---------------------------------------------------------------------------
// qkv_mfma: per (n, proj): Y[d][p] = sum_c W[d][c]*X[c][p] + bias[d]
// Block = 128 d x 128 p tile, 4 waves, each wave 64x64 (4x4 MFMA 16x16x32 tiles).
// Fragments loaded directly from global (cache-resident), no LDS.
// proj 0 -> Qw bf16 [n][d][p]; proj 1 -> Kw; proj 2 -> d_out fp32 [b][d][f][p].
// ---------------------------------------------------------------------------
__global__ __launch_bounds__(256) void qkv_mfma(
    const __hip_bfloat16* __restrict__ Wb, const __hip_bfloat16* __restrict__ Xt,
    const float* __restrict__ bq, const float* __restrict__ bk,
    const float* __restrict__ bv,
    __hip_bfloat16* __restrict__ Qw, __hip_bfloat16* __restrict__ Kw,
    float* __restrict__ Vout)
{
    const int p0 = blockIdx.x * 128, d0 = blockIdx.y * 128;
    const int z = blockIdx.z, proj = z % 3, n = z / 3;
    const int t = threadIdx.x, w = t >> 6, lane = t & 63;
    const int wd = (w >> 1) * 64, wp = (w & 1) * 64;
    const int q = lane >> 4, m16 = lane & 15;

    f32x4 acc[4][4];
    #pragma unroll
    for (int i = 0; i < 4; ++i)
        #pragma unroll
        for (int j = 0; j < 4; ++j)
            acc[i][j] = (f32x4){0.f, 0.f, 0.f, 0.f};

    // A frag: W[d = d0+wd+i*16+m16][c = c0 + q*8 .. +8]  (row-major, c contig)
    // B frag: Xt[p = p0+wp+j*16+m16][c = c0 + q*8 .. +8]  (row-major, c contig)
    const __hip_bfloat16* arow = Wb + (size_t)proj * CC * CC
                               + (size_t)(d0 + wd + m16) * CC + q * 8;
    const __hip_bfloat16* brow = Xt + (size_t)n * PP * CC
                               + (size_t)(p0 + wp + m16) * CC + q * 8;

    for (int c0 = 0; c0 < CC; c0 += 32) {
        bf16x8 a[4], b[4];
        #pragma unroll
        for (int i = 0; i < 4; ++i)
            a[i] = *reinterpret_cast<const bf16x8*>(arow + (size_t)i * 16 * CC + c0);
        #pragma unroll
        for (int j = 0; j < 4; ++j)
            b[j] = *reinterpret_cast<const bf16x8*>(brow + (size_t)j * 16 * CC + c0);
        #pragma unroll
        for (int i = 0; i < 4; ++i)
            #pragma unroll
            for (int j = 0; j < 4; ++j)
                acc[i][j] = __builtin_amdgcn_mfma_f32_16x16x32_bf16(a[i], b[j], acc[i][j], 0, 0, 0);
    }

    // Epilogue. D layout: col = lane&15 (p), row = q*4+reg (d), per 16x16 tile.
    if (proj < 2) {
        const float* bias = (proj == 0) ? bq : bk;
        __hip_bfloat16* dst = ((proj == 0) ? Qw : Kw) + (size_t)n * CC * PP;
        #pragma unroll
        for (int i = 0; i < 4; ++i)
            #pragma unroll
            for (int r = 0; r < 4; ++r) {
                const int d = d0 + wd + i * 16 + q * 4 + r;
                const float bb = bias[d];
                #pragma unroll
                for (int j = 0; j < 4; ++j) {
                    const int p = p0 + wp + j * 16 + m16;
                    dst[(size_t)d * PP + p] = __float2bfloat16(acc[i][j][r] + bb);
                }
            }
    } else {
        const int b = n >> 4, f = n & 15;
        #pragma unroll
        for (int i = 0; i < 4; ++i)
            #pragma unroll
            for (int r = 0; r < 4; ++r) {
                const int d = d0 + wd + i * 16 + q * 4 + r;
                const float bb = bv[d];
                #pragma unroll
                for (int j = 0; j < 4; ++j) {
                    const int p = p0 + wp + j * 16 + m16;
                    Vout[(((size_t)(b * CC + d)) * FF + f) * PP + p] = acc[i][j][r] + bb;
                }
            }
    }
}

// ---------------------------------------------------------------------------
// attn_out: per (b,d): wave0 computes S=Q·K^T/16 via MFMA (K=1024), softmax ->
// As in LDS; then all threads compute out[f1][p] = gamma*sum_f2 As[f1][f2]*V[f2][p] + x.
// V lives in d_out (in-place update; per-thread read-before-write).
// ---------------------------------------------------------------------------
__global__ __launch_bounds__(256) void attn_out(
    const __hip_bfloat16* __restrict__ Qw, const __hip_bfloat16* __restrict__ Kw,
    const float* __restrict__ x, const float* __restrict__ gamma,
    float* __restrict__ out)
{
    const int d = blockIdx.x, b = blockIdx.y;
    const int t = threadIdx.x;
    __shared__ float As[16][17];

    if (t < 64) {
        const int lane = t, q = lane >> 4, m16 = lane & 15;
        // A frag: Q[f1=m16][p chunk]; B frag: K[f2=m16][p chunk] — same address form
        const size_t gbase = ((size_t)(b * 16 + m16) * CC + d) * PP + q * 8;
        f32x4 acc0 = {0.f, 0.f, 0.f, 0.f}, acc1 = {0.f, 0.f, 0.f, 0.f};
        for (int p0 = 0; p0 < PP; p0 += 64) {
            bf16x8 aq0 = *reinterpret_cast<const bf16x8*>(Qw + gbase + p0);
            bf16x8 bk0 = *reinterpret_cast<const bf16x8*>(Kw + gbase + p0);
            bf16x8 aq1 = *reinterpret_cast<const bf16x8*>(Qw + gbase + p0 + 32);
            bf16x8 bk1 = *reinterpret_cast<const bf16x8*>(Kw + gbase + p0 + 32);
            acc0 = __builtin_amdgcn_mfma_f32_16x16x32_bf16(aq0, bk0, acc0, 0, 0, 0);
            acc1 = __builtin_amdgcn_mfma_f32_16x16x32_bf16(aq1, bk1, acc1, 0, 0, 0);
        }
        // lane holds S[f1=q*4+r][f2=m16]
        #pragma unroll
        for (int r = 0; r < 4; ++r) {
            const float s = (acc0[r] + acc1[r]) * 0.0625f;
            float m = s;
            #pragma unroll
            for (int off = 1; off < 16; off <<= 1) m = fmaxf(m, __shfl_xor(m, off));
            const float e = __expf(s - m);
            float den = e;
            #pragma unroll
            for (int off = 1; off < 16; off <<= 1) den += __shfl_xor(den, off);
            As[q * 4 + r][m16] = e / den;
        }
    }
    __syncthreads();

    const float g = gamma[0];
    const size_t base = ((size_t)(b * CC + d) * FF) * PP;
    #pragma unroll
    for (int i = 0; i < 4; ++i) {
        const int p = t + i * 256;
        float vv[16];
        #pragma unroll
        for (int f2 = 0; f2 < 16; ++f2) vv[f2] = out[base + (size_t)f2 * PP + p];
        float res[16];
        #pragma unroll
        for (int f1 = 0; f1 < 16; ++f1) {
            float a = 0.f;
            #pragma unroll
            for (int f2 = 0; f2 < 16; ++f2) a += As[f1][f2] * vv[f2];
            res[f1] = g * a + x[base + (size_t)f1 * PP + p];
        }
        #pragma unroll
        for (int f1 = 0; f1 < 16; ++f1) out[base + (size_t)f1 * PP + p] = res[f1];
    }
}

extern "C" void kernel_launch(void* const* d_in, const int* in_sizes, int n_in,
                              void* d_out, int out_size, void* d_ws, size_t ws_size,
                              hipStream_t stream) {
    const float* x     = (const float*)d_in[0];
    const float* wq    = (const float*)d_in[1];
    const float* bq    = (const float*)d_in[2];
    const float* wk    = (const float*)d_in[3];
    const float* bk    = (const float*)d_in[4];
    const float* wv    = (const float*)d_in[5];
    const float* bv    = (const float*)d_in[6];
    const float* gamma = (const float*)d_in[7];
    float* out = (float*)d_out;

    __hip_bfloat16* Qw = (__hip_bfloat16*)d_ws;                  // 32 MiB
    __hip_bfloat16* Kw = Qw + (size_t)NN * CC * PP;              // 32 MiB
    __hip_bfloat16* Xt = Kw + (size_t)NN * CC * PP;              // 32 MiB
    __hip_bfloat16* Wb = Xt + (size_t)NN * CC * PP;              // 384 KiB

    wconv_kernel<<<dim3(CC * CC / (256 * 4), 3), 256, 0, stream>>>(wq, wk, wv, Wb);
    xt_kernel<<<dim3(PP / 64, CC / 64, NN), 256, 0, stream>>>(x, Xt);
    qkv_mfma<<<dim3(PP / 128, CC / 128, NN * 3), 256, 0, stream>>>(
        Wb, Xt, bq, bk, bv, Qw, Kw, out);
    attn_out<<<dim3(CC, BB), 256, 0, stream>>>(Qw, Kw, x, gamma, out);
}

// Round 4
// 205.846 us; speedup vs baseline: 2.4357x; 1.3105x over previous
//
#include <hip/hip_runtime.h>
#include <hip/hip_bf16.h>

// Problem dims (hard-coded): B=4, C=256, F=16, H=32, W=32 (fp32 in/out)
#define CC 256
#define FF 16
#define PP 1024
#define BB 4
#define NN 64   // B*F

typedef __bf16 bf16x8 __attribute__((ext_vector_type(8)));
typedef float  f32x4  __attribute__((ext_vector_type(4)));

// async 16B global -> LDS (per-lane global addr; LDS dest = wave-uniform base + lane*16)
__device__ __forceinline__ void async16(const __hip_bfloat16* g, char* l) {
    __builtin_amdgcn_global_load_lds(
        (const __attribute__((address_space(1))) unsigned int*)g,
        (__attribute__((address_space(3))) unsigned int*)l, 16, 0, 0);
}

// ---------------------------------------------------------------------------
// xt_kernel: Xt[n][p][c] (bf16) = x[n][c][p] (fp32).  64x64 LDS tile transpose.
// ---------------------------------------------------------------------------
__global__ __launch_bounds__(256) void xt_kernel(
    const float* __restrict__ x, __hip_bfloat16* __restrict__ Xt)
{
    __shared__ float T[64][65];
    const int n = blockIdx.z, c0 = blockIdx.y * 64, p0 = blockIdx.x * 64;
    const int t = threadIdx.x;
    const int pl = t & 63, r0 = t >> 6;          // load: lane along p
    const float* xp = x + ((size_t)n * CC + c0) * PP + p0;
    #pragma unroll
    for (int i = 0; i < 16; ++i) {
        const int cl = r0 + i * 4;
        T[cl][pl] = xp[(size_t)cl * PP + pl];
    }
    __syncthreads();
    __hip_bfloat16* op = Xt + ((size_t)n * PP + p0) * CC + c0;
    const int cl2 = (t & 31) * 2, q0 = t >> 5;   // store: lane covers 2 c's
    #pragma unroll
    for (int j = 0; j < 8; ++j) {
        const int pr = q0 + j * 8;
        __hip_bfloat162 h;
        h.x = __float2bfloat16(T[cl2][pr]);
        h.y = __float2bfloat16(T[cl2 + 1][pr]);
        *(__hip_bfloat162*)(op + (size_t)pr * CC + cl2) = h;
    }
}

// ---------------------------------------------------------------------------
// wconv_kernel: Wb[proj][d][c] (bf16) from wq/wk/wv (fp32).
// ---------------------------------------------------------------------------
__global__ __launch_bounds__(256) void wconv_kernel(
    const float* __restrict__ wq, const float* __restrict__ wk,
    const float* __restrict__ wv, __hip_bfloat16* __restrict__ Wb)
{
    const int proj = blockIdx.y;
    const float* src = proj == 0 ? wq : (proj == 1 ? wk : wv);
    __hip_bfloat16* dst = Wb + (size_t)proj * CC * CC;
    const int idx = (blockIdx.x * 256 + threadIdx.x) * 4;
    const float4 v = *(const float4*)(src + idx);
    dst[idx + 0] = __float2bfloat16(v.x);
    dst[idx + 1] = __float2bfloat16(v.y);
    dst[idx + 2] = __float2bfloat16(v.z);
    dst[idx + 3] = __float2bfloat16(v.w);
}

// ---------------------------------------------------------------------------
// qkv_mfma (m97-style): per (n,proj): Y[d][p] = sum_c W[d][c]*X[c][p] + bias[d]
// 128d x 128p tile, BK=32, LDS staging via global_load_lds(16B) with XOR
// granule swizzle (col ^= (row>>1)&3) to spread ds_read_b128 over all banks.
// proj 0 -> Qw bf16 [n][d][p]; proj 1 -> Kw; proj 2 -> d_out fp32 [b][d][f][p].
// ---------------------------------------------------------------------------
__global__ __launch_bounds__(256) void qkv_mfma(
    const __hip_bfloat16* __restrict__ Wb, const __hip_bfloat16* __restrict__ Xt,
    const float* __restrict__ bq, const float* __restrict__ bk,
    const float* __restrict__ bv,
    __hip_bfloat16* __restrict__ Qw, __hip_bfloat16* __restrict__ Kw,
    float* __restrict__ Vout)
{
    __shared__ char lds[16384];   // A tile [128 rows][64 B] then B tile

    const int p0 = blockIdx.x * 128, d0 = blockIdx.y * 128;
    const int z = blockIdx.z, proj = z % 3, n = z / 3;
    const int t = threadIdx.x, w = t >> 6, lane = t & 63;
    const int wd = (w >> 1) * 64, wp = (w & 1) * 64;
    const int q = lane >> 4, m16 = lane & 15;

    // staging: slot s in [0,512), s0=t, s1=t+256; row=s>>2, col16=s&3,
    // global granule gcol = col16 ^ ((row>>1)&3)  (involution; row+64 same gcol)
    const int srow = t >> 2;
    const int gcol = (t & 3) ^ ((srow >> 1) & 3);
    const __hip_bfloat16* Abase = Wb + (size_t)proj * CC * CC
                                + (size_t)(d0 + srow) * CC + gcol * 8;
    const __hip_bfloat16* Bbase = Xt + (size_t)n * PP * CC
                                + (size_t)(p0 + srow) * CC + gcol * 8;
    char* ldsA0 = lds + t * 16;
    char* ldsA1 = lds + (t + 256) * 16;
    char* ldsB0 = lds + 8192 + t * 16;
    char* ldsB1 = lds + 8192 + (t + 256) * 16;

    // fragment read offsets (same swizzle)
    const int cxor = q ^ ((m16 >> 1) & 3);
    const int aoff = (wd + m16) * 64 + cxor * 16;          // + i*1024
    const int boff = 8192 + (wp + m16) * 64 + cxor * 16;   // + j*1024

    f32x4 acc[4][4];
    #pragma unroll
    for (int i = 0; i < 4; ++i)
        #pragma unroll
        for (int j = 0; j < 4; ++j)
            acc[i][j] = (f32x4){0.f, 0.f, 0.f, 0.f};

    for (int c0 = 0; c0 < CC; c0 += 32) {
        async16(Abase + c0, ldsA0);
        async16(Abase + 64 * CC + c0, ldsA1);
        async16(Bbase + c0, ldsB0);
        async16(Bbase + 64 * CC + c0, ldsB1);
        __syncthreads();

        bf16x8 a[4], b[4];
        #pragma unroll
        for (int i = 0; i < 4; ++i)
            a[i] = *(const bf16x8*)(lds + aoff + i * 1024);
        #pragma unroll
        for (int j = 0; j < 4; ++j)
            b[j] = *(const bf16x8*)(lds + boff + j * 1024);
        #pragma unroll
        for (int i = 0; i < 4; ++i)
            #pragma unroll
            for (int j = 0; j < 4; ++j)
                acc[i][j] = __builtin_amdgcn_mfma_f32_16x16x32_bf16(a[i], b[j], acc[i][j], 0, 0, 0);
        __syncthreads();
    }

    // Epilogue. D layout: col = lane&15 (p), row = q*4+reg (d), per 16x16 tile.
    if (proj < 2) {
        const float* bias = (proj == 0) ? bq : bk;
        __hip_bfloat16* dst = ((proj == 0) ? Qw : Kw) + (size_t)n * CC * PP;
        #pragma unroll
        for (int i = 0; i < 4; ++i)
            #pragma unroll
            for (int r = 0; r < 4; ++r) {
                const int d = d0 + wd + i * 16 + q * 4 + r;
                const float bb = bias[d];
                #pragma unroll
                for (int j = 0; j < 4; ++j) {
                    const int p = p0 + wp + j * 16 + m16;
                    dst[(size_t)d * PP + p] = __float2bfloat16(acc[i][j][r] + bb);
                }
            }
    } else {
        const int b = n >> 4, f = n & 15;
        #pragma unroll
        for (int i = 0; i < 4; ++i)
            #pragma unroll
            for (int r = 0; r < 4; ++r) {
                const int d = d0 + wd + i * 16 + q * 4 + r;
                const float bb = bv[d];
                #pragma unroll
                for (int j = 0; j < 4; ++j) {
                    const int p = p0 + wp + j * 16 + m16;
                    Vout[(((size_t)(b * CC + d)) * FF + f) * PP + p] = acc[i][j][r] + bb;
                }
            }
    }
}

// ---------------------------------------------------------------------------
// attn_out: per (b,d): all 4 waves compute partial S=Q·K^T over a 256-p chunk
// (MFMA), partials summed in LDS; softmax; then AV + gamma*out + x in place
// on d_out (V resides there), float2-vectorized.
// ---------------------------------------------------------------------------
__global__ __launch_bounds__(256) void attn_out(
    const __hip_bfloat16* __restrict__ Qw, const __hip_bfloat16* __restrict__ Kw,
    const float* __restrict__ x, const float* __restrict__ gamma,
    float* __restrict__ out)
{
    const int d = blockIdx.x, b = blockIdx.y;
    const int t = threadIdx.x, w = t >> 6, lane = t & 63;
    const int q = lane >> 4, m16 = lane & 15;
    __shared__ float Sp[4][16][17];
    __shared__ float As[16][17];

    // S partials: wave w covers p in [w*256, w*256+256)
    {
        const size_t gbase = ((size_t)(b * 16 + m16) * CC + d) * PP + w * 256 + q * 8;
        f32x4 acc0 = {0.f, 0.f, 0.f, 0.f}, acc1 = {0.f, 0.f, 0.f, 0.f};
        #pragma unroll
        for (int pc = 0; pc < 256; pc += 64) {
            bf16x8 aq0 = *(const bf16x8*)(Qw + gbase + pc);
            bf16x8 bk0 = *(const bf16x8*)(Kw + gbase + pc);
            bf16x8 aq1 = *(const bf16x8*)(Qw + gbase + pc + 32);
            bf16x8 bk1 = *(const bf16x8*)(Kw + gbase + pc + 32);
            acc0 = __builtin_amdgcn_mfma_f32_16x16x32_bf16(aq0, bk0, acc0, 0, 0, 0);
            acc1 = __builtin_amdgcn_mfma_f32_16x16x32_bf16(aq1, bk1, acc1, 0, 0, 0);
        }
        #pragma unroll
        for (int r = 0; r < 4; ++r)
            Sp[w][q * 4 + r][m16] = acc0[r] + acc1[r];
    }
    __syncthreads();

    // softmax: thread t handles (f1,f2) = (t>>4, t&15); 16-lane shuffle reduce
    {
        const int f1 = t >> 4, f2 = t & 15;
        const float s = (Sp[0][f1][f2] + Sp[1][f1][f2] + Sp[2][f1][f2] + Sp[3][f1][f2]) * 0.0625f;
        float m = s;
        #pragma unroll
        for (int off = 1; off < 16; off <<= 1) m = fmaxf(m, __shfl_xor(m, off));
        const float e = __expf(s - m);
        float den = e;
        #pragma unroll
        for (int off = 1; off < 16; off <<= 1) den += __shfl_xor(den, off);
        As[f1][f2] = e / den;
    }
    __syncthreads();

    // AV + epilogue, 2 p's per thread per iter (float2)
    const float g = gamma[0];
    const size_t base = ((size_t)(b * CC + d) * FF) * PP;
    #pragma unroll
    for (int i = 0; i < 2; ++i) {
        const int p = i * 512 + t * 2;
        float2 vv[16];
        #pragma unroll
        for (int f2 = 0; f2 < 16; ++f2)
            vv[f2] = *(const float2*)(out + base + (size_t)f2 * PP + p);
        #pragma unroll
        for (int f1 = 0; f1 < 16; ++f1) {
            float a0 = 0.f, a1 = 0.f;
            #pragma unroll
            for (int f2 = 0; f2 < 16; ++f2) {
                const float av = As[f1][f2];
                a0 += av * vv[f2].x;
                a1 += av * vv[f2].y;
            }
            const float2 xv = *(const float2*)(x + base + (size_t)f1 * PP + p);
            float2 res;
            res.x = g * a0 + xv.x;
            res.y = g * a1 + xv.y;
            *(float2*)(out + base + (size_t)f1 * PP + p) = res;
        }
    }
}

extern "C" void kernel_launch(void* const* d_in, const int* in_sizes, int n_in,
                              void* d_out, int out_size, void* d_ws, size_t ws_size,
                              hipStream_t stream) {
    const float* x     = (const float*)d_in[0];
    const float* wq    = (const float*)d_in[1];
    const float* bq    = (const float*)d_in[2];
    const float* wk    = (const float*)d_in[3];
    const float* bk    = (const float*)d_in[4];
    const float* wv    = (const float*)d_in[5];
    const float* bv    = (const float*)d_in[6];
    const float* gamma = (const float*)d_in[7];
    float* out = (float*)d_out;

    __hip_bfloat16* Qw = (__hip_bfloat16*)d_ws;                  // 32 MiB
    __hip_bfloat16* Kw = Qw + (size_t)NN * CC * PP;              // 32 MiB
    __hip_bfloat16* Xt = Kw + (size_t)NN * CC * PP;              // 32 MiB
    __hip_bfloat16* Wb = Xt + (size_t)NN * CC * PP;              // 384 KiB

    wconv_kernel<<<dim3(CC * CC / (256 * 4), 3), 256, 0, stream>>>(wq, wk, wv, Wb);
    xt_kernel<<<dim3(PP / 64, CC / 64, NN), 256, 0, stream>>>(x, Xt);
    qkv_mfma<<<dim3(PP / 128, CC / 128, NN * 3), 256, 0, stream>>>(
        Wb, Xt, bq, bk, bv, Qw, Kw, out);
    attn_out<<<dim3(CC, BB), 256, 0, stream>>>(Qw, Kw, x, gamma, out);
}

// Round 5
// 199.807 us; speedup vs baseline: 2.5093x; 1.0302x over previous
//
#include <hip/hip_runtime.h>
#include <hip/hip_bf16.h>

// Problem dims (hard-coded): B=4, C=256, F=16, H=32, W=32 (fp32 in/out)
#define CC 256
#define FF 16
#define PP 1024
#define BB 4
#define NN 64   // B*F

typedef __bf16 bf16x8 __attribute__((ext_vector_type(8)));
typedef float  f32x4  __attribute__((ext_vector_type(4)));

// async 16B global -> LDS (per-lane global addr; LDS dest = wave-uniform base + lane*16)
__device__ __forceinline__ void async16(const __hip_bfloat16* g, char* l) {
    __builtin_amdgcn_global_load_lds(
        (const __attribute__((address_space(1))) unsigned int*)g,
        (__attribute__((address_space(3))) unsigned int*)l, 16, 0, 0);
}

// ---------------------------------------------------------------------------
// xt_kernel: Xt[n][p][c] (bf16) = x[n][c][p] (fp32).  64x64 LDS tile transpose.
// ---------------------------------------------------------------------------
__global__ __launch_bounds__(256) void xt_kernel(
    const float* __restrict__ x, __hip_bfloat16* __restrict__ Xt)
{
    __shared__ float T[64][65];
    const int n = blockIdx.z, c0 = blockIdx.y * 64, p0 = blockIdx.x * 64;
    const int t = threadIdx.x;
    const int pl = t & 63, r0 = t >> 6;          // load: lane along p
    const float* xp = x + ((size_t)n * CC + c0) * PP + p0;
    #pragma unroll
    for (int i = 0; i < 16; ++i) {
        const int cl = r0 + i * 4;
        T[cl][pl] = xp[(size_t)cl * PP + pl];
    }
    __syncthreads();
    __hip_bfloat16* op = Xt + ((size_t)n * PP + p0) * CC + c0;
    const int cl2 = (t & 31) * 2, q0 = t >> 5;   // store: lane covers 2 c's
    #pragma unroll
    for (int j = 0; j < 8; ++j) {
        const int pr = q0 + j * 8;
        __hip_bfloat162 h;
        h.x = __float2bfloat16(T[cl2][pr]);
        h.y = __float2bfloat16(T[cl2 + 1][pr]);
        *(__hip_bfloat162*)(op + (size_t)pr * CC + cl2) = h;
    }
}

// ---------------------------------------------------------------------------
// wconv_kernel: Wb[proj][d][c] (bf16) from wq/wk/wv (fp32).
// ---------------------------------------------------------------------------
__global__ __launch_bounds__(256) void wconv_kernel(
    const float* __restrict__ wq, const float* __restrict__ wk,
    const float* __restrict__ wv, __hip_bfloat16* __restrict__ Wb)
{
    const int proj = blockIdx.y;
    const float* src = proj == 0 ? wq : (proj == 1 ? wk : wv);
    __hip_bfloat16* dst = Wb + (size_t)proj * CC * CC;
    const int idx = (blockIdx.x * 256 + threadIdx.x) * 4;
    const float4 v = *(const float4*)(src + idx);
    dst[idx + 0] = __float2bfloat16(v.x);
    dst[idx + 1] = __float2bfloat16(v.y);
    dst[idx + 2] = __float2bfloat16(v.z);
    dst[idx + 3] = __float2bfloat16(v.w);
}

// ---------------------------------------------------------------------------
// qkv_mfma: per (n,proj): Y[d][p] = sum_c W[d][c]*X[c][p] + bias[d]
// 128d x 128p tile, BK=64, LDS staging via global_load_lds(16B) with XOR
// granule swizzle (gc = col ^ (row&7)).  Epilogue bounces acc through a
// per-wave padded LDS tile (stride 144B) to emit coalesced 16B stores.
// proj 0 -> Qw bf16 [n][d][p]; proj 1 -> Kw; proj 2 -> d_out fp32 [b][d][f][p].
// ---------------------------------------------------------------------------
__global__ __launch_bounds__(256) void qkv_mfma(
    const __hip_bfloat16* __restrict__ Wb, const __hip_bfloat16* __restrict__ Xt,
    const float* __restrict__ bq, const float* __restrict__ bk,
    const float* __restrict__ bv,
    __hip_bfloat16* __restrict__ Qw, __hip_bfloat16* __restrict__ Kw,
    float* __restrict__ Vout)
{
    __shared__ char lds[36864];   // staging: A 16K + B 16K; bounce: 4 x 9216

    const int p0 = blockIdx.x * 128, d0 = blockIdx.y * 128;
    const int z = blockIdx.z, proj = z % 3, n = z / 3;
    const int t = threadIdx.x, w = t >> 6, lane = t & 63;
    const int wd = (w >> 1) * 64, wp = (w & 1) * 64;
    const int q = lane >> 4, m16 = lane & 15;

    const __hip_bfloat16* Abase = Wb + (size_t)proj * CC * CC + (size_t)d0 * CC;
    const __hip_bfloat16* Bbase = Xt + (size_t)n * PP * CC + (size_t)p0 * CC;

    f32x4 acc[4][4];
    #pragma unroll
    for (int i = 0; i < 4; ++i)
        #pragma unroll
        for (int j = 0; j < 4; ++j)
            acc[i][j] = (f32x4){0.f, 0.f, 0.f, 0.f};

    for (int c0 = 0; c0 < CC; c0 += 64) {
        // stage: tile rows 0..127, 8 granules of 16B per row; slot s = t + 256k
        #pragma unroll
        for (int k = 0; k < 4; ++k) {
            const int s = t + 256 * k;
            const int row = s >> 3;
            const int gc = (s & 7) ^ (row & 7);
            async16(Abase + (size_t)row * CC + c0 + gc * 8, lds + s * 16);
            async16(Bbase + (size_t)row * CC + c0 + gc * 8, lds + 16384 + s * 16);
        }
        __syncthreads();
        #pragma unroll
        for (int kk = 0; kk < 2; ++kk) {
            bf16x8 a[4], b[4];
            #pragma unroll
            for (int i = 0; i < 4; ++i) {
                const int row = wd + i * 16 + m16;
                const int col = (4 * kk + q) ^ (row & 7);
                a[i] = *(const bf16x8*)(lds + row * 128 + col * 16);
            }
            #pragma unroll
            for (int j = 0; j < 4; ++j) {
                const int row = wp + j * 16 + m16;
                const int col = (4 * kk + q) ^ (row & 7);
                b[j] = *(const bf16x8*)(lds + 16384 + row * 128 + col * 16);
            }
            #pragma unroll
            for (int i = 0; i < 4; ++i)
                #pragma unroll
                for (int j = 0; j < 4; ++j)
                    acc[i][j] = __builtin_amdgcn_mfma_f32_16x16x32_bf16(a[i], b[j], acc[i][j], 0, 0, 0);
        }
        __syncthreads();
    }

    // ---- epilogue: bounce through per-wave LDS tile, emit coalesced stores ----
    __syncthreads();                       // all frag reads of staging done
    char* wb = lds + w * 9216;             // 64 rows x 144 B
    const int dl2 = lane >> 3, pl2 = lane & 7;

    if (proj < 2) {
        const float* bias = (proj == 0) ? bq : bk;
        #pragma unroll
        for (int i = 0; i < 4; ++i)
            #pragma unroll
            for (int r = 0; r < 4; ++r) {
                const int d_l = i * 16 + q * 4 + r;
                const float bb = bias[d0 + wd + d_l];
                #pragma unroll
                for (int j = 0; j < 4; ++j) {
                    const int p_l = j * 16 + m16;
                    *(__hip_bfloat16*)(wb + d_l * 144 + p_l * 2) =
                        __float2bfloat16(acc[i][j][r] + bb);
                }
            }
        __hip_bfloat16* dst = ((proj == 0) ? Qw : Kw) + (size_t)n * CC * PP;
        #pragma unroll
        for (int k = 0; k < 8; ++k) {
            const int d_l = k * 8 + dl2;
            bf16x8 v = *(const bf16x8*)(wb + d_l * 144 + pl2 * 16);
            *(bf16x8*)(dst + (size_t)(d0 + wd + d_l) * PP + p0 + wp + pl2 * 8) = v;
        }
    } else {
        const int b = n >> 4, f = n & 15;
        #pragma unroll
        for (int h = 0; h < 2; ++h) {
            #pragma unroll
            for (int i = 0; i < 4; ++i)
                #pragma unroll
                for (int r = 0; r < 4; ++r) {
                    const int d_l = i * 16 + q * 4 + r;
                    const float bb = bv[d0 + wd + d_l];
                    #pragma unroll
                    for (int jj = 0; jj < 2; ++jj) {
                        const int j = 2 * h + jj;
                        const int p_rel = jj * 16 + m16;
                        *(float*)(wb + d_l * 144 + p_rel * 4) = acc[i][j][r] + bb;
                    }
                }
            #pragma unroll
            for (int k = 0; k < 8; ++k) {
                const int d_l = k * 8 + dl2;
                f32x4 v = *(const f32x4*)(wb + d_l * 144 + pl2 * 16);
                const int p = p0 + wp + h * 32 + pl2 * 4;
                *(f32x4*)(Vout + (((size_t)(b * CC + d0 + wd + d_l)) * FF + f) * PP + p) = v;
            }
        }
    }
}

// ---------------------------------------------------------------------------
// attn_out: per (b,d): 4 waves compute partial S=Q·K^T over 256-p chunks
// (MFMA), partials summed in LDS; softmax; then AV + gamma*out + x in place
// on d_out (V resides there), float4-vectorized (thread t owns p=4t..4t+3).
// ---------------------------------------------------------------------------
__global__ __launch_bounds__(256) void attn_out(
    const __hip_bfloat16* __restrict__ Qw, const __hip_bfloat16* __restrict__ Kw,
    const float* __restrict__ x, const float* __restrict__ gamma,
    float* __restrict__ out)
{
    const int d = blockIdx.x, b = blockIdx.y;
    const int t = threadIdx.x, w = t >> 6, lane = t & 63;
    const int q = lane >> 4, m16 = lane & 15;
    __shared__ float Sp[4][16][17];
    __shared__ float As[16][17];

    // S partials: wave w covers p in [w*256, w*256+256)
    {
        const size_t gbase = ((size_t)(b * 16 + m16) * CC + d) * PP + w * 256 + q * 8;
        f32x4 acc0 = {0.f, 0.f, 0.f, 0.f}, acc1 = {0.f, 0.f, 0.f, 0.f};
        #pragma unroll
        for (int pc = 0; pc < 256; pc += 64) {
            bf16x8 aq0 = *(const bf16x8*)(Qw + gbase + pc);
            bf16x8 bk0 = *(const bf16x8*)(Kw + gbase + pc);
            bf16x8 aq1 = *(const bf16x8*)(Qw + gbase + pc + 32);
            bf16x8 bk1 = *(const bf16x8*)(Kw + gbase + pc + 32);
            acc0 = __builtin_amdgcn_mfma_f32_16x16x32_bf16(aq0, bk0, acc0, 0, 0, 0);
            acc1 = __builtin_amdgcn_mfma_f32_16x16x32_bf16(aq1, bk1, acc1, 0, 0, 0);
        }
        #pragma unroll
        for (int r = 0; r < 4; ++r)
            Sp[w][q * 4 + r][m16] = acc0[r] + acc1[r];
    }
    __syncthreads();

    // softmax: thread t handles (f1,f2) = (t>>4, t&15); 16-lane shuffle reduce
    {
        const int f1 = t >> 4, f2 = t & 15;
        const float s = (Sp[0][f1][f2] + Sp[1][f1][f2] + Sp[2][f1][f2] + Sp[3][f1][f2]) * 0.0625f;
        float m = s;
        #pragma unroll
        for (int off = 1; off < 16; off <<= 1) m = fmaxf(m, __shfl_xor(m, off));
        const float e = __expf(s - m);
        float den = e;
        #pragma unroll
        for (int off = 1; off < 16; off <<= 1) den += __shfl_xor(den, off);
        As[f1][f2] = e / den;
    }
    __syncthreads();

    // AV + epilogue: thread t owns p = 4t..4t+3 (read all V before writing)
    const float g = gamma[0];
    const size_t base = ((size_t)(b * CC + d) * FF) * PP + t * 4;
    f32x4 vv[16];
    #pragma unroll
    for (int f2 = 0; f2 < 16; ++f2)
        vv[f2] = *(const f32x4*)(out + base + (size_t)f2 * PP);
    #pragma unroll
    for (int f1 = 0; f1 < 16; ++f1) {
        f32x4 a = {0.f, 0.f, 0.f, 0.f};
        #pragma unroll
        for (int f2 = 0; f2 < 16; ++f2) {
            const float av = As[f1][f2];
            a += av * vv[f2];
        }
        const f32x4 xv = *(const f32x4*)(x + base + (size_t)f1 * PP);
        const f32x4 res = g * a + xv;
        *(f32x4*)(out + base + (size_t)f1 * PP) = res;
    }
}

extern "C" void kernel_launch(void* const* d_in, const int* in_sizes, int n_in,
                              void* d_out, int out_size, void* d_ws, size_t ws_size,
                              hipStream_t stream) {
    const float* x     = (const float*)d_in[0];
    const float* wq    = (const float*)d_in[1];
    const float* bq    = (const float*)d_in[2];
    const float* wk    = (const float*)d_in[3];
    const float* bk    = (const float*)d_in[4];
    const float* wv    = (const float*)d_in[5];
    const float* bv    = (const float*)d_in[6];
    const float* gamma = (const float*)d_in[7];
    float* out = (float*)d_out;

    __hip_bfloat16* Qw = (__hip_bfloat16*)d_ws;                  // 32 MiB
    __hip_bfloat16* Kw = Qw + (size_t)NN * CC * PP;              // 32 MiB
    __hip_bfloat16* Xt = Kw + (size_t)NN * CC * PP;              // 32 MiB
    __hip_bfloat16* Wb = Xt + (size_t)NN * CC * PP;              // 384 KiB

    wconv_kernel<<<dim3(CC * CC / (256 * 4), 3), 256, 0, stream>>>(wq, wk, wv, Wb);
    xt_kernel<<<dim3(PP / 64, CC / 64, NN), 256, 0, stream>>>(x, Xt);
    qkv_mfma<<<dim3(PP / 128, CC / 128, NN * 3), 256, 0, stream>>>(
        Wb, Xt, bq, bk, bv, Qw, Kw, out);
    attn_out<<<dim3(CC, BB), 256, 0, stream>>>(Qw, Kw, x, gamma, out);
}